// Round 2
// baseline (756.966 us; speedup 1.0000x reference)
//
#include <hip/hip_runtime.h>
#include <math.h>

// Problem constants
#define B_   8
#define P_   1024
#define D_   768
#define NEGV -1000000000.0f

// ---------------------------------------------------------------------------
// Kernel A: fp32 GEMM replicating OpenBLAS sgemm accumulation. ROUND-9:
// panel-1 sums held in a SECOND register accumulator (acc1) instead of the
// round-7 global spill (fp32 store/load is lossless -> bit-identical bracket
// (p1+p2)+bias), and kc-step 16->32 (halves barrier pairs 96->48, same
// ascending-d fma chain per output within each 384 panel -> bit-exact).
// Removes 216 MB of HBM spill traffic + the serialized reload epilogue.
// NOTE: dbuf/prefetch variants measured WORSE in earlier rounds (r6 530us,
// r8 630us @ VGPR 188) — do not re-add pipelining here.
// (ROUND-10: resubmission of round-9 source verbatim — round-9 bench was an
// infra failure: "MI355X container failed twice", no measurement taken.)
// ---------------------------------------------------------------------------
__global__ __launch_bounds__(256, 2) void gemm_qkv_np(
    const float* __restrict__ x,
    const float* __restrict__ Wq, const float* __restrict__ bq,
    const float* __restrict__ Wk, const float* __restrict__ bk,
    const float* __restrict__ Wv, const float* __restrict__ bv,
    float* __restrict__ Qo, float* __restrict__ Ko, float* __restrict__ Vo)
{
    const int which = blockIdx.z;
    const float* __restrict__ W    = (which == 0) ? Wq : (which == 1) ? Wk : Wv;
    const float* __restrict__ bias = (which == 0) ? bq : (which == 1) ? bk : bv;
    float* __restrict__ Out        = (which == 0) ? Qo : (which == 1) ? Ko : Vo;

    const int n0 = blockIdx.x * 128;
    const int m0 = blockIdx.y * 128;
    const int t  = threadIdx.x;
    const int tx = t & 15, ty = t >> 4;

    __shared__ float As[32 * 132];   // As[d][row], stride 132, d = 0..31
    __shared__ float Bs[32 * 132];   // Bs[d][col]

    const int  ra  = t >> 2, ca = t & 3;
    const int  ar0 = m0 + ra;
    const int  ar1 = m0 + ra + 64;
    const long a_off0 = ((long)(ar0 >> 10) * 1025 + 1 + (ar0 & 1023)) * D_; // skip token 0
    const long a_off1 = ((long)(ar1 >> 10) * 1025 + 1 + (ar1 & 1023)) * D_;
    const int  db = t >> 5, cb = t & 31;

    float acc1[8][8] = {};   // panel 1 (d = 0..383)
    float acc2[8][8] = {};   // panel 2 (d = 384..767)

#define STAGE_TILE(D0)                                                                              \
    {                                                                                               \
        float4 av00 = *reinterpret_cast<const float4*>(x + a_off0 + (D0) + 4 * ca);                 \
        float4 av01 = *reinterpret_cast<const float4*>(x + a_off0 + (D0) + 16 + 4 * ca);            \
        float4 av10 = *reinterpret_cast<const float4*>(x + a_off1 + (D0) + 4 * ca);                 \
        float4 av11 = *reinterpret_cast<const float4*>(x + a_off1 + (D0) + 16 + 4 * ca);            \
        float4 bw0 = *reinterpret_cast<const float4*>(W + (long)((D0) + db) * D_ + n0 + 4 * cb);    \
        float4 bw1 = *reinterpret_cast<const float4*>(W + (long)((D0) + db + 8) * D_ + n0 + 4 * cb);\
        float4 bw2 = *reinterpret_cast<const float4*>(W + (long)((D0) + db + 16) * D_ + n0 + 4 * cb);\
        float4 bw3 = *reinterpret_cast<const float4*>(W + (long)((D0) + db + 24) * D_ + n0 + 4 * cb);\
        __syncthreads();                                                                            \
        As[(4 * ca + 0) * 132 + ra]       = av00.x;                                                 \
        As[(4 * ca + 1) * 132 + ra]       = av00.y;                                                 \
        As[(4 * ca + 2) * 132 + ra]       = av00.z;                                                 \
        As[(4 * ca + 3) * 132 + ra]       = av00.w;                                                 \
        As[(4 * ca + 16) * 132 + ra]      = av01.x;                                                 \
        As[(4 * ca + 17) * 132 + ra]      = av01.y;                                                 \
        As[(4 * ca + 18) * 132 + ra]      = av01.z;                                                 \
        As[(4 * ca + 19) * 132 + ra]      = av01.w;                                                 \
        As[(4 * ca + 0) * 132 + ra + 64]  = av10.x;                                                 \
        As[(4 * ca + 1) * 132 + ra + 64]  = av10.y;                                                 \
        As[(4 * ca + 2) * 132 + ra + 64]  = av10.z;                                                 \
        As[(4 * ca + 3) * 132 + ra + 64]  = av10.w;                                                 \
        As[(4 * ca + 16) * 132 + ra + 64] = av11.x;                                                 \
        As[(4 * ca + 17) * 132 + ra + 64] = av11.y;                                                 \
        As[(4 * ca + 18) * 132 + ra + 64] = av11.z;                                                 \
        As[(4 * ca + 19) * 132 + ra + 64] = av11.w;                                                 \
        *reinterpret_cast<float4*>(&Bs[(db + 0) * 132 + 4 * cb])  = bw0;                            \
        *reinterpret_cast<float4*>(&Bs[(db + 8) * 132 + 4 * cb])  = bw1;                            \
        *reinterpret_cast<float4*>(&Bs[(db + 16) * 132 + 4 * cb]) = bw2;                            \
        *reinterpret_cast<float4*>(&Bs[(db + 24) * 132 + 4 * cb]) = bw3;                            \
        __syncthreads();                                                                            \
    }

#define COMPUTE32(ACC)                                                                              \
    _Pragma("unroll")                                                                               \
    for (int d = 0; d < 32; ++d) {                                                                  \
        float4 a0 = *reinterpret_cast<const float4*>(&As[d * 132 + 8 * ty]);                        \
        float4 a1 = *reinterpret_cast<const float4*>(&As[d * 132 + 8 * ty + 4]);                    \
        float4 b0 = *reinterpret_cast<const float4*>(&Bs[d * 132 + 8 * tx]);                        \
        float4 b1 = *reinterpret_cast<const float4*>(&Bs[d * 132 + 8 * tx + 4]);                    \
        float a[8] = {a0.x, a0.y, a0.z, a0.w, a1.x, a1.y, a1.z, a1.w};                              \
        float b[8] = {b0.x, b0.y, b0.z, b0.w, b1.x, b1.y, b1.z, b1.w};                              \
        _Pragma("unroll")                                                                           \
        for (int i = 0; i < 8; ++i)                                                                 \
            _Pragma("unroll")                                                                       \
            for (int j = 0; j < 8; ++j)                                                             \
                ACC[i][j] = fmaf(a[i], b[j], ACC[i][j]);                                            \
    }

    // ---- pass 1: d = 0..383 (first kc=384 panel) ----
    for (int d0 = 0; d0 < 384; d0 += 32) {
        STAGE_TILE(d0);
        COMPUTE32(acc1);
    }

    // ---- pass 2: d = 384..767 (second kc=384 panel) ----
    for (int d0 = 384; d0 < 768; d0 += 32) {
        STAGE_TILE(d0);
        COMPUTE32(acc2);
    }

#undef STAGE_TILE
#undef COMPUTE32

    // epilogue: exact round-3 bracket (p1 + p2) + bias, p1 from registers
    float bcol[8];
#pragma unroll
    for (int u = 0; u < 2; ++u) {
        float4 bb = *reinterpret_cast<const float4*>(bias + n0 + 8 * tx + 4 * u);
        bcol[4 * u + 0] = bb.x; bcol[4 * u + 1] = bb.y;
        bcol[4 * u + 2] = bb.z; bcol[4 * u + 3] = bb.w;
    }
#pragma unroll
    for (int i = 0; i < 8; ++i) {
        const long r = m0 + 8 * ty + i;
        float* orow = Out + r * D_ + n0 + 8 * tx;
#pragma unroll
        for (int u = 0; u < 2; ++u) {
            float4 o;
            float s0 = __fadd_rn(acc1[i][4 * u + 0], acc2[i][4 * u + 0]);
            float s1 = __fadd_rn(acc1[i][4 * u + 1], acc2[i][4 * u + 1]);
            float s2 = __fadd_rn(acc1[i][4 * u + 2], acc2[i][4 * u + 2]);
            float s3 = __fadd_rn(acc1[i][4 * u + 3], acc2[i][4 * u + 3]);
            o.x = __fadd_rn(s0, bcol[4 * u + 0]);
            o.y = __fadd_rn(s1, bcol[4 * u + 1]);
            o.z = __fadd_rn(s2, bcol[4 * u + 2]);
            o.w = __fadd_rn(s3, bcol[4 * u + 3]);
            *reinterpret_cast<float4*>(orow + 4 * u) = o;
        }
    }
}

// ---------------------------------------------------------------------------
// Kernel B: row L2-normalize replicating numpy pairwise tree (VERBATIM).
// ---------------------------------------------------------------------------
__global__ __launch_bounds__(256) void l2norm_np(float* __restrict__ Q,
                                                 float* __restrict__ K)
{
    const int gid  = blockIdx.x * 256 + threadIdx.x;
    const int w    = gid >> 6;
    const int lane = gid & 63;
    const int wl   = threadIdx.x >> 6;
    float* __restrict__ base = (w < 8192) ? Q : K;
    const long row = (long)(w & 8191);
    float* p = base + row * D_;

    const int bb = lane >> 3, jj = lane & 7;
    const float* seg = p + 96 * bb + jj;
    float r = 0.0f;
#pragma unroll
    for (int i = 0; i < 12; ++i) {
        float xv = seg[8 * i];
        r = __fadd_rn(r, __fmul_rn(xv, xv));
    }

    __shared__ float red[4][64];
    red[wl][lane] = r;
    __syncthreads();

    float Bv[8];
#pragma unroll
    for (int b2 = 0; b2 < 8; ++b2) {
        const float* rr = &red[wl][8 * b2];
        float t1 = __fadd_rn(rr[0], rr[1]);
        float t2 = __fadd_rn(rr[2], rr[3]);
        float t3 = __fadd_rn(rr[4], rr[5]);
        float t4 = __fadd_rn(rr[6], rr[7]);
        Bv[b2] = __fadd_rn(__fadd_rn(t1, t2), __fadd_rn(t3, t4));
    }
    float s01 = __fadd_rn(Bv[0], Bv[1]), s23 = __fadd_rn(Bv[2], Bv[3]);
    float s45 = __fadd_rn(Bv[4], Bv[5]), s67 = __fadd_rn(Bv[6], Bv[7]);
    float tot = __fadd_rn(__fadd_rn(s01, s23), __fadd_rn(s45, s67));

    const float nm = fmaxf(__fsqrt_rn(tot), 1e-12f);

    float* q = p + lane * 12;
#pragma unroll
    for (int i = 0; i < 12; ++i) q[i] = __fdiv_rn(q[i], nm);
}

// ---------------------------------------------------------------------------
// Kernel C: scores, quad-split numpy 16-chain tree. kc=32 (VERBATIM).
// ---------------------------------------------------------------------------
__global__ __launch_bounds__(256) void scores_np(
    const float* __restrict__ Q, const float* __restrict__ K,
    const float* __restrict__ pb, float* __restrict__ S)
{
    const int bz = blockIdx.z;
    const int n0 = blockIdx.x * 32;   // cols
    const int m0 = blockIdx.y * 32;   // rows
    const int t  = threadIdx.x;
    const int q    = t & 3;           // chain-slot lane within quad
    const int quad = t >> 2;          // 0..63
    const int qx   = quad & 7;        // col group (4 cols)
    const int qy   = quad >> 3;       // row group (4 rows)

    __shared__ float Qs[32 * 36];     // [dd][row], stride 36, dd = 0..31
    __shared__ float Ks[32 * 36];     // [dd][col]

    const float* Qb = Q + (((long)bz << 10) + m0) * D_;
    const float* Kb = K + (((long)bz << 10) + n0) * D_;

    // staging: t<128 -> Q tile, t>=128 -> K tile; 32 rows x 4 d-groups;
    // each thread stages d-groups sg (dd=4sg..4sg+3) and sg+4 (dd=16+4sg..).
    const int sr = (t & 127) >> 2;    // row 0..31
    const int sg = t & 3;             // d-group 0..3
    const float* gsrc = (t < 128) ? (Qb + (long)sr * D_ + 4 * sg)
                                  : (Kb + (long)sr * D_ + 4 * sg);
    float* lw = (t < 128) ? Qs : Ks;

    float acc[4][4][4] = {};          // [chain-slot][i][j]

    for (int d0 = 0; d0 < D_; d0 += 32) {
        __syncthreads();
        float4 g0 = *reinterpret_cast<const float4*>(gsrc + d0);
        float4 g1 = *reinterpret_cast<const float4*>(gsrc + d0 + 16);
        lw[(4 * sg + 0) * 36 + sr]      = g0.x;
        lw[(4 * sg + 1) * 36 + sr]      = g0.y;
        lw[(4 * sg + 2) * 36 + sr]      = g0.z;
        lw[(4 * sg + 3) * 36 + sr]      = g0.w;
        lw[(4 * sg + 16) * 36 + sr]     = g1.x;
        lw[(4 * sg + 17) * 36 + sr]     = g1.y;
        lw[(4 * sg + 18) * 36 + sr]     = g1.z;
        lw[(4 * sg + 19) * 36 + sr]     = g1.w;
        __syncthreads();

#pragma unroll
        for (int s = 0; s < 8; ++s) {
            const int dd = q + 4 * (s & 3) + 16 * (s >> 2);   // s<4: q+4s, s>=4: +16
            const int c  = s & 3;                             // accumulator slot
            float4 qv = *reinterpret_cast<const float4*>(&Qs[dd * 36 + 4 * qy]);
            float4 kv = *reinterpret_cast<const float4*>(&Ks[dd * 36 + 4 * qx]);
            float a[4] = {qv.x, qv.y, qv.z, qv.w};
            float b[4] = {kv.x, kv.y, kv.z, kv.w};
#pragma unroll
            for (int i = 0; i < 4; ++i)
#pragma unroll
                for (int j = 0; j < 4; ++j)
                    acc[c][i][j] = fmaf(a[i], b[j], acc[c][i][j]);
        }
    }

    // chains on lane q: slot0=chain q, slot1=q+4, slot2=q+8, slot3=q+12
    // y[q]=slot0+slot2, y[q+4]=slot1+slot3, z[q]=y[q]+y[q+4],
    // dot=(z0+z2)+(z1+z3) via 2 shfl_xor adds.
    float dot[4][4];
#pragma unroll
    for (int i = 0; i < 4; ++i)
#pragma unroll
        for (int j = 0; j < 4; ++j) {
            float ylo = __fadd_rn(acc[0][i][j], acc[2][i][j]);
            float yhi = __fadd_rn(acc[1][i][j], acc[3][i][j]);
            float zz  = __fadd_rn(ylo, yhi);
            float zr  = __shfl_xor(zz, 2, 64);
            float t2  = __fadd_rn(zz, zr);          // lane0: z0+z2, lane1: z1+z3
            float tr  = __shfl_xor(t2, 1, 64);
            dot[i][j] = __fadd_rn(t2, tr);          // lane0: (z0+z2)+(z1+z3)
        }

    if (q == 0) {
        const int c0 = n0 + 4 * qx;
#pragma unroll
        for (int i = 0; i < 4; ++i) {
            const int p = m0 + 4 * qy + i;
            float4 pbv = *reinterpret_cast<const float4*>(pb + (long)p * P_ + c0);
            float v[4] = {__fadd_rn(dot[i][0], pbv.x), __fadd_rn(dot[i][1], pbv.y),
                          __fadd_rn(dot[i][2], pbv.z), __fadd_rn(dot[i][3], pbv.w)};
#pragma unroll
            for (int j = 0; j < 4; ++j)
                if (c0 + j == p) v[j] = NEGV;
            float4 o = {v[0], v[1], v[2], v[3]};
            *reinterpret_cast<float4*>(S + (((long)bz << 10) + p) * P_ + c0) = o;
        }
    }
}

// ---------------------------------------------------------------------------
// Kernel D: top-16 + softmax + V gather (VERBATIM).
// ---------------------------------------------------------------------------
__global__ __launch_bounds__(256) void topk_np(
    const float* __restrict__ S, const float* __restrict__ V,
    float* __restrict__ out)
{
    const int gid  = blockIdx.x * 256 + threadIdx.x;
    const int gw   = gid >> 6;          // row id 0..8191
    const int lane = gid & 63;
    const int b    = gw >> 10;

    const float* srow = S + ((long)gw << 10);
    float s[16];
#pragma unroll
    for (int t = 0; t < 16; ++t) s[t] = __fdiv_rn(srow[lane + 64 * t], 0.1f);

    float topv[16];
    int   topi[16];
#pragma unroll
    for (int r = 0; r < 16; ++r) {
        float bvv = s[0];
        int   bt  = 0;
#pragma unroll
        for (int t = 1; t < 16; ++t)
            if (s[t] > bvv) { bvv = s[t]; bt = t; }
        int bi = lane + 64 * bt;
#pragma unroll
        for (int m = 1; m < 64; m <<= 1) {
            float ov = __shfl_xor(bvv, m, 64);
            int   oi = __shfl_xor(bi, m, 64);
            if (ov > bvv || (ov == bvv && oi < bi)) { bvv = ov; bi = oi; }
        }
        topv[r] = bvv;
        topi[r] = bi;
#pragma unroll
        for (int t = 0; t < 16; ++t)
            if (lane + 64 * t == bi) s[t] = -3.0e38f;
    }

    const float mx = topv[0];
    float e[16];
#pragma unroll
    for (int r = 0; r < 16; ++r) e[r] = expf(topv[r] - mx);
    float r8[8];
#pragma unroll
    for (int j = 0; j < 8; ++j) r8[j] = __fadd_rn(e[j], e[j + 8]);
    float t1 = __fadd_rn(r8[0], r8[1]);
    float t2 = __fadd_rn(r8[2], r8[3]);
    float t3 = __fadd_rn(r8[4], r8[5]);
    float t4 = __fadd_rn(r8[6], r8[7]);
    float sum = __fadd_rn(__fadd_rn(t1, t2), __fadd_rn(t3, t4));
    float wgt[16];
#pragma unroll
    for (int r = 0; r < 16; ++r) wgt[r] = __fdiv_rn(e[r], sum);

    float4 a0 = {0, 0, 0, 0}, a1 = {0, 0, 0, 0}, a2 = {0, 0, 0, 0};
    const float* vb = V + ((long)b << 10) * D_;
#pragma unroll
    for (int r = 0; r < 16; ++r) {
        const float* vr = vb + (long)topi[r] * D_ + lane * 12;
        const float wr = wgt[r];
        float4 x0 = *reinterpret_cast<const float4*>(vr);
        float4 x1 = *reinterpret_cast<const float4*>(vr + 4);
        float4 x2 = *reinterpret_cast<const float4*>(vr + 8);
        a0.x = fmaf(wr, x0.x, a0.x); a0.y = fmaf(wr, x0.y, a0.y);
        a0.z = fmaf(wr, x0.z, a0.z); a0.w = fmaf(wr, x0.w, a0.w);
        a1.x = fmaf(wr, x1.x, a1.x); a1.y = fmaf(wr, x1.y, a1.y);
        a1.z = fmaf(wr, x1.z, a1.z); a1.w = fmaf(wr, x1.w, a1.w);
        a2.x = fmaf(wr, x2.x, a2.x); a2.y = fmaf(wr, x2.y, a2.y);
        a2.z = fmaf(wr, x2.z, a2.z); a2.w = fmaf(wr, x2.w, a2.w);
    }
    float* orow = out + (long)gw * D_ + lane * 12;
    *reinterpret_cast<float4*>(orow)     = a0;
    *reinterpret_cast<float4*>(orow + 4) = a1;
    *reinterpret_cast<float4*>(orow + 8) = a2;
}

// ---------------------------------------------------------------------------
extern "C" void kernel_launch(void* const* d_in, const int* in_sizes, int n_in,
                              void* d_out, int out_size, void* d_ws, size_t ws_size,
                              hipStream_t stream)
{
    const float* x  = (const float*)d_in[0];
    const float* Wq = (const float*)d_in[1];
    const float* bq = (const float*)d_in[2];
    const float* Wk = (const float*)d_in[3];
    const float* bk = (const float*)d_in[4];
    const float* Wv = (const float*)d_in[5];
    const float* bv = (const float*)d_in[6];
    const float* pb = (const float*)d_in[7];
    float* out = (float*)d_out;

    // Workspace (fp32): Q | K | V (8192x768 each) | S (8192x1024)
    float* ws = (float*)d_ws;
    float* Q = ws;
    float* K = Q + (size_t)B_ * P_ * D_;
    float* V = K + (size_t)B_ * P_ * D_;
    float* S = V + (size_t)B_ * P_ * D_;

    hipLaunchKernelGGL(gemm_qkv_np, dim3(6, 64, 3), dim3(256), 0, stream,
                       x, Wq, bq, Wk, bk, Wv, bv, Q, K, V);
    hipLaunchKernelGGL(l2norm_np, dim3(4096), dim3(256), 0, stream, Q, K);
    hipLaunchKernelGGL(scores_np, dim3(32, 32, 8), dim3(256), 0, stream,
                       Q, K, pb, S);
    hipLaunchKernelGGL(topk_np, dim3(2048), dim3(256), 0, stream,
                       S, V, out);
}

// Round 4
// 740.192 us; speedup vs baseline: 1.0227x; 1.0227x over previous
//
#include <hip/hip_runtime.h>
#include <math.h>

// Problem constants
#define B_   8
#define P_   1024
#define D_   768
#define NEGV -1000000000.0f

// ---------------------------------------------------------------------------
// Kernel A: fp32 GEMM replicating OpenBLAS sgemm accumulation. ROUND-12:
// verbatim resubmission of R11 (r7 spill structure + kc32). R11's bench died
// with SIGABRT in pytest with no compile error; kernel audited in-bounds
// (max x idx 6,297,599 < 6,297,600; W 589,823 < 589,824; LDS rows <= 31)
// and numerically identical to r7 (passed, 737us). Diagnosis: infra flake
// (R1 container double-fail, R2 425s push anomaly). If this aborts again,
// it's reproducible -> bisect by reverting kc32.
// POST-MORTEM r9: dual accumulator forced VGPR cap 128 + scratch spill.
// Do NOT hold both panels in registers. dbuf/prefetch measured worse
// (r6 530us, r8 630us) — do not re-add pipelining.
// ---------------------------------------------------------------------------
__global__ __launch_bounds__(256) void gemm_qkv_np(
    const float* __restrict__ x,
    const float* __restrict__ Wq, const float* __restrict__ bq,
    const float* __restrict__ Wk, const float* __restrict__ bk,
    const float* __restrict__ Wv, const float* __restrict__ bv,
    float* __restrict__ Qo, float* __restrict__ Ko, float* __restrict__ Vo)
{
    const int which = blockIdx.z;
    const float* __restrict__ W    = (which == 0) ? Wq : (which == 1) ? Wk : Wv;
    const float* __restrict__ bias = (which == 0) ? bq : (which == 1) ? bk : bv;
    float* __restrict__ Out        = (which == 0) ? Qo : (which == 1) ? Ko : Vo;

    const int n0 = blockIdx.x * 128;
    const int m0 = blockIdx.y * 128;
    const int t  = threadIdx.x;
    const int tx = t & 15, ty = t >> 4;

    __shared__ float As[32 * 132];   // As[d][row], stride 132, d = 0..31
    __shared__ float Bs[32 * 132];   // Bs[d][col]

    const int  ra  = t >> 2, ca = t & 3;
    const int  ar0 = m0 + ra;
    const int  ar1 = m0 + ra + 64;
    const long a_off0 = ((long)(ar0 >> 10) * 1025 + 1 + (ar0 & 1023)) * D_; // skip token 0
    const long a_off1 = ((long)(ar1 >> 10) * 1025 + 1 + (ar1 & 1023)) * D_;
    const int  db = t >> 5, cb = t & 31;

    float acc[8][8] = {};

#define STAGE_TILE(D0)                                                                              \
    {                                                                                               \
        float4 av00 = *reinterpret_cast<const float4*>(x + a_off0 + (D0) + 4 * ca);                 \
        float4 av01 = *reinterpret_cast<const float4*>(x + a_off0 + (D0) + 16 + 4 * ca);            \
        float4 av10 = *reinterpret_cast<const float4*>(x + a_off1 + (D0) + 4 * ca);                 \
        float4 av11 = *reinterpret_cast<const float4*>(x + a_off1 + (D0) + 16 + 4 * ca);            \
        float4 bw0 = *reinterpret_cast<const float4*>(W + (long)((D0) + db) * D_ + n0 + 4 * cb);    \
        float4 bw1 = *reinterpret_cast<const float4*>(W + (long)((D0) + db + 8) * D_ + n0 + 4 * cb);\
        float4 bw2 = *reinterpret_cast<const float4*>(W + (long)((D0) + db + 16) * D_ + n0 + 4 * cb);\
        float4 bw3 = *reinterpret_cast<const float4*>(W + (long)((D0) + db + 24) * D_ + n0 + 4 * cb);\
        __syncthreads();                                                                            \
        As[(4 * ca + 0) * 132 + ra]       = av00.x;                                                 \
        As[(4 * ca + 1) * 132 + ra]       = av00.y;                                                 \
        As[(4 * ca + 2) * 132 + ra]       = av00.z;                                                 \
        As[(4 * ca + 3) * 132 + ra]       = av00.w;                                                 \
        As[(4 * ca + 16) * 132 + ra]      = av01.x;                                                 \
        As[(4 * ca + 17) * 132 + ra]      = av01.y;                                                 \
        As[(4 * ca + 18) * 132 + ra]      = av01.z;                                                 \
        As[(4 * ca + 19) * 132 + ra]      = av01.w;                                                 \
        As[(4 * ca + 0) * 132 + ra + 64]  = av10.x;                                                 \
        As[(4 * ca + 1) * 132 + ra + 64]  = av10.y;                                                 \
        As[(4 * ca + 2) * 132 + ra + 64]  = av10.z;                                                 \
        As[(4 * ca + 3) * 132 + ra + 64]  = av10.w;                                                 \
        As[(4 * ca + 16) * 132 + ra + 64] = av11.x;                                                 \
        As[(4 * ca + 17) * 132 + ra + 64] = av11.y;                                                 \
        As[(4 * ca + 18) * 132 + ra + 64] = av11.z;                                                 \
        As[(4 * ca + 19) * 132 + ra + 64] = av11.w;                                                 \
        *reinterpret_cast<float4*>(&Bs[(db + 0) * 132 + 4 * cb])  = bw0;                            \
        *reinterpret_cast<float4*>(&Bs[(db + 8) * 132 + 4 * cb])  = bw1;                            \
        *reinterpret_cast<float4*>(&Bs[(db + 16) * 132 + 4 * cb]) = bw2;                            \
        *reinterpret_cast<float4*>(&Bs[(db + 24) * 132 + 4 * cb]) = bw3;                            \
        __syncthreads();                                                                            \
    }

#define COMPUTE32(ACC)                                                                              \
    _Pragma("unroll")                                                                               \
    for (int d = 0; d < 32; ++d) {                                                                  \
        float4 a0 = *reinterpret_cast<const float4*>(&As[d * 132 + 8 * ty]);                        \
        float4 a1 = *reinterpret_cast<const float4*>(&As[d * 132 + 8 * ty + 4]);                    \
        float4 b0 = *reinterpret_cast<const float4*>(&Bs[d * 132 + 8 * tx]);                        \
        float4 b1 = *reinterpret_cast<const float4*>(&Bs[d * 132 + 8 * tx + 4]);                    \
        float a[8] = {a0.x, a0.y, a0.z, a0.w, a1.x, a1.y, a1.z, a1.w};                              \
        float b[8] = {b0.x, b0.y, b0.z, b0.w, b1.x, b1.y, b1.z, b1.w};                              \
        _Pragma("unroll")                                                                           \
        for (int i = 0; i < 8; ++i)                                                                 \
            _Pragma("unroll")                                                                       \
            for (int j = 0; j < 8; ++j)                                                             \
                ACC[i][j] = fmaf(a[i], b[j], ACC[i][j]);                                            \
    }

    // ---- pass 1: d = 0..383 (first kc=384 panel) ----
    for (int d0 = 0; d0 < 384; d0 += 32) {
        STAGE_TILE(d0);
        COMPUTE32(acc);
    }

    // spill panel-1 raw sums to Out (overwritten by the epilogue below)
#pragma unroll
    for (int i = 0; i < 8; ++i) {
        const long r = m0 + 8 * ty + i;
        float* orow = Out + r * D_ + n0 + 8 * tx;
        float4 o0 = {acc[i][0], acc[i][1], acc[i][2], acc[i][3]};
        float4 o1 = {acc[i][4], acc[i][5], acc[i][6], acc[i][7]};
        *reinterpret_cast<float4*>(orow)     = o0;
        *reinterpret_cast<float4*>(orow + 4) = o1;
#pragma unroll
        for (int j = 0; j < 8; ++j) acc[i][j] = 0.0f;
    }

    // ---- pass 2: d = 384..767 (second kc=384 panel) ----
    for (int d0 = 384; d0 < 768; d0 += 32) {
        STAGE_TILE(d0);
        COMPUTE32(acc);
    }

#undef STAGE_TILE
#undef COMPUTE32

    // epilogue: reload panel-1, exact round-3 bracket (p1 + p2) + bias
    float bcol[8];
#pragma unroll
    for (int u = 0; u < 2; ++u) {
        float4 bb = *reinterpret_cast<const float4*>(bias + n0 + 8 * tx + 4 * u);
        bcol[4 * u + 0] = bb.x; bcol[4 * u + 1] = bb.y;
        bcol[4 * u + 2] = bb.z; bcol[4 * u + 3] = bb.w;
    }
#pragma unroll
    for (int i = 0; i < 8; ++i) {
        const long r = m0 + 8 * ty + i;
        float* orow = Out + r * D_ + n0 + 8 * tx;
        float4 p10 = *reinterpret_cast<float4*>(orow);
        float4 p11 = *reinterpret_cast<float4*>(orow + 4);
        float p1[8] = {p10.x, p10.y, p10.z, p10.w, p11.x, p11.y, p11.z, p11.w};
#pragma unroll
        for (int u = 0; u < 2; ++u) {
            float4 o;
            float s0 = __fadd_rn(p1[4 * u + 0], acc[i][4 * u + 0]);
            float s1 = __fadd_rn(p1[4 * u + 1], acc[i][4 * u + 1]);
            float s2 = __fadd_rn(p1[4 * u + 2], acc[i][4 * u + 2]);
            float s3 = __fadd_rn(p1[4 * u + 3], acc[i][4 * u + 3]);
            o.x = __fadd_rn(s0, bcol[4 * u + 0]);
            o.y = __fadd_rn(s1, bcol[4 * u + 1]);
            o.z = __fadd_rn(s2, bcol[4 * u + 2]);
            o.w = __fadd_rn(s3, bcol[4 * u + 3]);
            *reinterpret_cast<float4*>(orow + 4 * u) = o;
        }
    }
}

// ---------------------------------------------------------------------------
// Kernel B: row L2-normalize replicating numpy pairwise tree (VERBATIM).
// ---------------------------------------------------------------------------
__global__ __launch_bounds__(256) void l2norm_np(float* __restrict__ Q,
                                                 float* __restrict__ K)
{
    const int gid  = blockIdx.x * 256 + threadIdx.x;
    const int w    = gid >> 6;
    const int lane = gid & 63;
    const int wl   = threadIdx.x >> 6;
    float* __restrict__ base = (w < 8192) ? Q : K;
    const long row = (long)(w & 8191);
    float* p = base + row * D_;

    const int bb = lane >> 3, jj = lane & 7;
    const float* seg = p + 96 * bb + jj;
    float r = 0.0f;
#pragma unroll
    for (int i = 0; i < 12; ++i) {
        float xv = seg[8 * i];
        r = __fadd_rn(r, __fmul_rn(xv, xv));
    }

    __shared__ float red[4][64];
    red[wl][lane] = r;
    __syncthreads();

    float Bv[8];
#pragma unroll
    for (int b2 = 0; b2 < 8; ++b2) {
        const float* rr = &red[wl][8 * b2];
        float t1 = __fadd_rn(rr[0], rr[1]);
        float t2 = __fadd_rn(rr[2], rr[3]);
        float t3 = __fadd_rn(rr[4], rr[5]);
        float t4 = __fadd_rn(rr[6], rr[7]);
        Bv[b2] = __fadd_rn(__fadd_rn(t1, t2), __fadd_rn(t3, t4));
    }
    float s01 = __fadd_rn(Bv[0], Bv[1]), s23 = __fadd_rn(Bv[2], Bv[3]);
    float s45 = __fadd_rn(Bv[4], Bv[5]), s67 = __fadd_rn(Bv[6], Bv[7]);
    float tot = __fadd_rn(__fadd_rn(s01, s23), __fadd_rn(s45, s67));

    const float nm = fmaxf(__fsqrt_rn(tot), 1e-12f);

    float* q = p + lane * 12;
#pragma unroll
    for (int i = 0; i < 12; ++i) q[i] = __fdiv_rn(q[i], nm);
}

// ---------------------------------------------------------------------------
// Kernel C: scores, quad-split numpy 16-chain tree. kc=32 (VERBATIM).
// ---------------------------------------------------------------------------
__global__ __launch_bounds__(256) void scores_np(
    const float* __restrict__ Q, const float* __restrict__ K,
    const float* __restrict__ pb, float* __restrict__ S)
{
    const int bz = blockIdx.z;
    const int n0 = blockIdx.x * 32;   // cols
    const int m0 = blockIdx.y * 32;   // rows
    const int t  = threadIdx.x;
    const int q    = t & 3;           // chain-slot lane within quad
    const int quad = t >> 2;          // 0..63
    const int qx   = quad & 7;        // col group (4 cols)
    const int qy   = quad >> 3;       // row group (4 rows)

    __shared__ float Qs[32 * 36];     // [dd][row], stride 36, dd = 0..31
    __shared__ float Ks[32 * 36];     // [dd][col]

    const float* Qb = Q + (((long)bz << 10) + m0) * D_;
    const float* Kb = K + (((long)bz << 10) + n0) * D_;

    // staging: t<128 -> Q tile, t>=128 -> K tile; 32 rows x 4 d-groups;
    // each thread stages d-groups sg (dd=4sg..4sg+3) and sg+4 (dd=16+4sg..).
    const int sr = (t & 127) >> 2;    // row 0..31
    const int sg = t & 3;             // d-group 0..3
    const float* gsrc = (t < 128) ? (Qb + (long)sr * D_ + 4 * sg)
                                  : (Kb + (long)sr * D_ + 4 * sg);
    float* lw = (t < 128) ? Qs : Ks;

    float acc[4][4][4] = {};          // [chain-slot][i][j]

    for (int d0 = 0; d0 < D_; d0 += 32) {
        __syncthreads();
        float4 g0 = *reinterpret_cast<const float4*>(gsrc + d0);
        float4 g1 = *reinterpret_cast<const float4*>(gsrc + d0 + 16);
        lw[(4 * sg + 0) * 36 + sr]      = g0.x;
        lw[(4 * sg + 1) * 36 + sr]      = g0.y;
        lw[(4 * sg + 2) * 36 + sr]      = g0.z;
        lw[(4 * sg + 3) * 36 + sr]      = g0.w;
        lw[(4 * sg + 16) * 36 + sr]     = g1.x;
        lw[(4 * sg + 17) * 36 + sr]     = g1.y;
        lw[(4 * sg + 18) * 36 + sr]     = g1.z;
        lw[(4 * sg + 19) * 36 + sr]     = g1.w;
        __syncthreads();

#pragma unroll
        for (int s = 0; s < 8; ++s) {
            const int dd = q + 4 * (s & 3) + 16 * (s >> 2);   // s<4: q+4s, s>=4: +16
            const int c  = s & 3;                             // accumulator slot
            float4 qv = *reinterpret_cast<const float4*>(&Qs[dd * 36 + 4 * qy]);
            float4 kv = *reinterpret_cast<const float4*>(&Ks[dd * 36 + 4 * qx]);
            float a[4] = {qv.x, qv.y, qv.z, qv.w};
            float b[4] = {kv.x, kv.y, kv.z, kv.w};
#pragma unroll
            for (int i = 0; i < 4; ++i)
#pragma unroll
                for (int j = 0; j < 4; ++j)
                    acc[c][i][j] = fmaf(a[i], b[j], acc[c][i][j]);
        }
    }

    // chains on lane q: slot0=chain q, slot1=q+4, slot2=q+8, slot3=q+12
    // y[q]=slot0+slot2, y[q+4]=slot1+slot3, z[q]=y[q]+y[q+4],
    // dot=(z0+z2)+(z1+z3) via 2 shfl_xor adds.
    float dot[4][4];
#pragma unroll
    for (int i = 0; i < 4; ++i)
#pragma unroll
        for (int j = 0; j < 4; ++j) {
            float ylo = __fadd_rn(acc[0][i][j], acc[2][i][j]);
            float yhi = __fadd_rn(acc[1][i][j], acc[3][i][j]);
            float zz  = __fadd_rn(ylo, yhi);
            float zr  = __shfl_xor(zz, 2, 64);
            float t2  = __fadd_rn(zz, zr);          // lane0: z0+z2, lane1: z1+z3
            float tr  = __shfl_xor(t2, 1, 64);
            dot[i][j] = __fadd_rn(t2, tr);          // lane0: (z0+z2)+(z1+z3)
        }

    if (q == 0) {
        const int c0 = n0 + 4 * qx;
#pragma unroll
        for (int i = 0; i < 4; ++i) {
            const int p = m0 + 4 * qy + i;
            float4 pbv = *reinterpret_cast<const float4*>(pb + (long)p * P_ + c0);
            float v[4] = {__fadd_rn(dot[i][0], pbv.x), __fadd_rn(dot[i][1], pbv.y),
                          __fadd_rn(dot[i][2], pbv.z), __fadd_rn(dot[i][3], pbv.w)};
#pragma unroll
            for (int j = 0; j < 4; ++j)
                if (c0 + j == p) v[j] = NEGV;
            float4 o = {v[0], v[1], v[2], v[3]};
            *reinterpret_cast<float4*>(S + (((long)bz << 10) + p) * P_ + c0) = o;
        }
    }
}

// ---------------------------------------------------------------------------
// Kernel D: top-16 + softmax + V gather (VERBATIM).
// ---------------------------------------------------------------------------
__global__ __launch_bounds__(256) void topk_np(
    const float* __restrict__ S, const float* __restrict__ V,
    float* __restrict__ out)
{
    const int gid  = blockIdx.x * 256 + threadIdx.x;
    const int gw   = gid >> 6;          // row id 0..8191
    const int lane = gid & 63;
    const int b    = gw >> 10;

    const float* srow = S + ((long)gw << 10);
    float s[16];
#pragma unroll
    for (int t = 0; t < 16; ++t) s[t] = __fdiv_rn(srow[lane + 64 * t], 0.1f);

    float topv[16];
    int   topi[16];
#pragma unroll
    for (int r = 0; r < 16; ++r) {
        float bvv = s[0];
        int   bt  = 0;
#pragma unroll
        for (int t = 1; t < 16; ++t)
            if (s[t] > bvv) { bvv = s[t]; bt = t; }
        int bi = lane + 64 * bt;
#pragma unroll
        for (int m = 1; m < 64; m <<= 1) {
            float ov = __shfl_xor(bvv, m, 64);
            int   oi = __shfl_xor(bi, m, 64);
            if (ov > bvv || (ov == bvv && oi < bi)) { bvv = ov; bi = oi; }
        }
        topv[r] = bvv;
        topi[r] = bi;
#pragma unroll
        for (int t = 0; t < 16; ++t)
            if (lane + 64 * t == bi) s[t] = -3.0e38f;
    }

    const float mx = topv[0];
    float e[16];
#pragma unroll
    for (int r = 0; r < 16; ++r) e[r] = expf(topv[r] - mx);
    float r8[8];
#pragma unroll
    for (int j = 0; j < 8; ++j) r8[j] = __fadd_rn(e[j], e[j + 8]);
    float t1 = __fadd_rn(r8[0], r8[1]);
    float t2 = __fadd_rn(r8[2], r8[3]);
    float t3 = __fadd_rn(r8[4], r8[5]);
    float t4 = __fadd_rn(r8[6], r8[7]);
    float sum = __fadd_rn(__fadd_rn(t1, t2), __fadd_rn(t3, t4));
    float wgt[16];
#pragma unroll
    for (int r = 0; r < 16; ++r) wgt[r] = __fdiv_rn(e[r], sum);

    float4 a0 = {0, 0, 0, 0}, a1 = {0, 0, 0, 0}, a2 = {0, 0, 0, 0};
    const float* vb = V + ((long)b << 10) * D_;
#pragma unroll
    for (int r = 0; r < 16; ++r) {
        const float* vr = vb + (long)topi[r] * D_ + lane * 12;
        const float wr = wgt[r];
        float4 x0 = *reinterpret_cast<const float4*>(vr);
        float4 x1 = *reinterpret_cast<const float4*>(vr + 4);
        float4 x2 = *reinterpret_cast<const float4*>(vr + 8);
        a0.x = fmaf(wr, x0.x, a0.x); a0.y = fmaf(wr, x0.y, a0.y);
        a0.z = fmaf(wr, x0.z, a0.z); a0.w = fmaf(wr, x0.w, a0.w);
        a1.x = fmaf(wr, x1.x, a1.x); a1.y = fmaf(wr, x1.y, a1.y);
        a1.z = fmaf(wr, x1.z, a1.z); a1.w = fmaf(wr, x1.w, a1.w);
        a2.x = fmaf(wr, x2.x, a2.x); a2.y = fmaf(wr, x2.y, a2.y);
        a2.z = fmaf(wr, x2.z, a2.z); a2.w = fmaf(wr, x2.w, a2.w);
    }
    float* orow = out + (long)gw * D_ + lane * 12;
    *reinterpret_cast<float4*>(orow)     = a0;
    *reinterpret_cast<float4*>(orow + 4) = a1;
    *reinterpret_cast<float4*>(orow + 8) = a2;
}

// ---------------------------------------------------------------------------
extern "C" void kernel_launch(void* const* d_in, const int* in_sizes, int n_in,
                              void* d_out, int out_size, void* d_ws, size_t ws_size,
                              hipStream_t stream)
{
    const float* x  = (const float*)d_in[0];
    const float* Wq = (const float*)d_in[1];
    const float* bq = (const float*)d_in[2];
    const float* Wk = (const float*)d_in[3];
    const float* bk = (const float*)d_in[4];
    const float* Wv = (const float*)d_in[5];
    const float* bv = (const float*)d_in[6];
    const float* pb = (const float*)d_in[7];
    float* out = (float*)d_out;

    // Workspace (fp32): Q | K | V (8192x768 each) | S (8192x1024)
    float* ws = (float*)d_ws;
    float* Q = ws;
    float* K = Q + (size_t)B_ * P_ * D_;
    float* V = K + (size_t)B_ * P_ * D_;
    float* S = V + (size_t)B_ * P_ * D_;

    hipLaunchKernelGGL(gemm_qkv_np, dim3(6, 64, 3), dim3(256), 0, stream,
                       x, Wq, bq, Wk, bk, Wv, bv, Q, K, V);
    hipLaunchKernelGGL(l2norm_np, dim3(4096), dim3(256), 0, stream, Q, K);
    hipLaunchKernelGGL(scores_np, dim3(32, 32, 8), dim3(256), 0, stream,
                       Q, K, pb, S);
    hipLaunchKernelGGL(topk_np, dim3(2048), dim3(256), 0, stream,
                       S, V, out);
}